// Round 1
// baseline (582.632 us; speedup 1.0000x reference)
//
#include <hip/hip_runtime.h>
#include <math.h>

#define BB 16
#define MM 512
#define LL 1024
#define DD 128
#define KK 16
#define HH 8
#define DHH 16
#define NDFF 512
#define NNODE (BB*MM)      // 8192
#define NEDGE (NNODE*KK)   // 131072

// ---------------- column means: mu[b,m] = mean_l x_enc[b,l,m] ----------------
__global__ void colmean_kernel(const float* __restrict__ X, float* __restrict__ mu) {
  int bm = blockIdx.x * 256 + threadIdx.x;          // 0..8191
  int b = bm >> 9, m = bm & (MM - 1);
  const float* p = X + (size_t)b * LL * MM + m;
  float s = 0.f;
  #pragma unroll 4
  for (int l = 0; l < LL; ++l) s += p[(size_t)l * MM];
  mu[bm] = s * (1.f / 1024.f);
}

// ---------------- raw Gram G = X^T X per batch, symmetric tile pairs ----------------
__global__ __launch_bounds__(256) void gram_kernel(const float* __restrict__ X,
                                                   float* __restrict__ G) {
  int b = blockIdx.y;
  int pi = blockIdx.x;                 // 0..35 upper-triangular tile pairs (8x8 tiles)
  int ti = 0, rem = pi;
  while (rem >= 8 - ti) { rem -= 8 - ti; ++ti; }
  int tj = ti + rem;
  int m0 = ti * 64, n0 = tj * 64;
  __shared__ float As[32][64];
  __shared__ float Bs[32][64];
  int tid = threadIdx.x;
  int ty = tid >> 4, tx = tid & 15;
  float acc[4][4] = {};
  const float* Xb = X + (size_t)b * LL * MM;
  for (int l0 = 0; l0 < LL; l0 += 32) {
    int rr = tid >> 3, cc = (tid & 7) * 8;
    const float* p = Xb + (size_t)(l0 + rr) * MM + m0 + cc;
    const float* q = Xb + (size_t)(l0 + rr) * MM + n0 + cc;
    float4 a0 = *(const float4*)p;
    float4 a1 = *(const float4*)(p + 4);
    float4 c0 = *(const float4*)q;
    float4 c1 = *(const float4*)(q + 4);
    *(float4*)&As[rr][cc]     = a0;
    *(float4*)&As[rr][cc + 4] = a1;
    *(float4*)&Bs[rr][cc]     = c0;
    *(float4*)&Bs[rr][cc + 4] = c1;
    __syncthreads();
    #pragma unroll
    for (int kk = 0; kk < 32; ++kk) {
      float4 a4 = *(const float4*)&As[kk][ty * 4];
      float4 b4 = *(const float4*)&Bs[kk][tx * 4];
      acc[0][0] += a4.x * b4.x; acc[0][1] += a4.x * b4.y; acc[0][2] += a4.x * b4.z; acc[0][3] += a4.x * b4.w;
      acc[1][0] += a4.y * b4.x; acc[1][1] += a4.y * b4.y; acc[1][2] += a4.y * b4.z; acc[1][3] += a4.y * b4.w;
      acc[2][0] += a4.z * b4.x; acc[2][1] += a4.z * b4.y; acc[2][2] += a4.z * b4.z; acc[2][3] += a4.z * b4.w;
      acc[3][0] += a4.w * b4.x; acc[3][1] += a4.w * b4.y; acc[3][2] += a4.w * b4.z; acc[3][3] += a4.w * b4.w;
    }
    __syncthreads();
  }
  float* Gb = G + (size_t)b * MM * MM;
  #pragma unroll
  for (int i = 0; i < 4; ++i) {
    #pragma unroll
    for (int j = 0; j < 4; ++j) {
      int r = m0 + ty * 4 + i, c = n0 + tx * 4 + j;
      Gb[(size_t)r * MM + c] = acc[i][j];
      if (ti != tj) Gb[(size_t)c * MM + r] = acc[i][j];
    }
  }
}

// ---------------- rstd[b,m] = 1/std (std==0 -> 1) ----------------
__global__ void rstd_kernel(const float* __restrict__ G, const float* __restrict__ mu,
                            float* __restrict__ rstd) {
  int bm = blockIdx.x * 256 + threadIdx.x;
  int b = bm >> 9, m = bm & (MM - 1);
  float g = G[(size_t)b * MM * MM + (size_t)m * MM + m];
  float mm = mu[bm];
  float cov = (g - 1024.f * mm * mm) * (1.f / 1023.f);
  float sd = sqrtf(fmaxf(cov, 0.f));
  rstd[bm] = (sd == 0.f) ? 1.f : (1.f / sd);
}

// ---------------- neighbors: ascending stable argsort positions 1..16 ----------------
__global__ void select_kernel(const float* __restrict__ G, const float* __restrict__ mu,
                              const float* __restrict__ rstd, int* __restrict__ nb) {
  int w = threadIdx.x >> 6, lane = threadIdx.x & 63;
  int bm = blockIdx.x * 4 + w;
  int b = bm >> 9, m = bm & (MM - 1);
  const float* Gr = G + (size_t)b * MM * MM + (size_t)m * MM;
  const float* mub = mu + b * MM;
  const float* rsb = rstd + b * MM;
  float mm = mub[m], rm = rsb[m];
  float vals[8];
  int excl = 0;
  #pragma unroll
  for (int j = 0; j < 8; ++j) {
    int n = lane + j * 64;
    float cov = (Gr[n] - 1024.f * mm * mub[n]) * (1.f / 1023.f);
    vals[j] = cov * rm * rsb[n];
  }
  int* out = nb + (size_t)bm * KK;
  for (int it = 0; it < KK + 1; ++it) {
    float bv = 1e30f; int bi = 1 << 30;
    #pragma unroll
    for (int j = 0; j < 8; ++j) {
      if (!((excl >> j) & 1)) {
        int n = lane + j * 64;
        if (vals[j] < bv) { bv = vals[j]; bi = n; }   // strict < keeps smaller n on ties
      }
    }
    for (int off = 32; off; off >>= 1) {
      float v2 = __shfl_down(bv, off);
      int   i2 = __shfl_down(bi, off);
      if (v2 < bv || (v2 == bv && i2 < bi)) { bv = v2; bi = i2; }
    }
    bi = __shfl(bi, 0);
    if ((bi & 63) == lane) excl |= 1 << (bi >> 6);
    if (it > 0 && lane == 0) out[it - 1] = bi;
  }
}

// ---------------- degree counts (without self-loop) ----------------
__global__ void count_kernel(const int* __restrict__ nb, int* __restrict__ cnt) {
  int e = blockIdx.x * 256 + threadIdx.x;           // < NEDGE
  int b = e >> 13, i = e & 8191;
  int dst = b * MM + nb[(size_t)b * 8192 + i];
  atomicAdd(&cnt[dst], 1);
}

// ---------------- exclusive scan + cursor + dinv (single block) ----------------
__global__ void scan_kernel(const int* __restrict__ cnt, int* __restrict__ offs,
                            int* __restrict__ curs, float* __restrict__ dinv) {
  __shared__ int part[256];
  int tid = threadIdx.x;
  int base = tid * 32;
  int local[32];
  int s = 0;
  #pragma unroll
  for (int i = 0; i < 32; ++i) { local[i] = cnt[base + i]; s += local[i]; }
  part[tid] = s;
  __syncthreads();
  for (int off = 1; off < 256; off <<= 1) {
    int v = (tid >= off) ? part[tid - off] : 0;
    __syncthreads();
    part[tid] += v;
    __syncthreads();
  }
  int run = part[tid] - s;   // exclusive base of this chunk
  #pragma unroll
  for (int i = 0; i < 32; ++i) {
    int n = base + i;
    offs[n] = run; curs[n] = run;
    run += local[i];
    dinv[n] = rsqrtf((float)(local[i] + 1));   // +1 = self loop
  }
  if (tid == 255) offs[NNODE] = run;
}

// ---------------- scatter reverse edge lists ----------------
__global__ void scatter_kernel(const int* __restrict__ nb, int* __restrict__ curs,
                               int* __restrict__ lists) {
  int e = blockIdx.x * 256 + threadIdx.x;
  int b = e >> 13, i = e & 8191;
  int dst = b * MM + nb[(size_t)b * 8192 + i];
  int src = b * MM + (i & (MM - 1));
  int pos = atomicAdd(&curs[dst], 1);
  lists[pos] = src;
}

// ---------------- GCN aggregation: out = relu(dinv[n]*(sum dinv[s]*xw[s] + dinv[n]*xw[n]) + b) --------
__global__ void agg_kernel(const float* __restrict__ xw, const float* __restrict__ dinv,
                           const int* __restrict__ offs, const int* __restrict__ lists,
                           const float* __restrict__ bias, float* __restrict__ out) {
  int n = blockIdx.x * 2 + (threadIdx.x >> 7);
  int c = threadIdx.x & 127;
  float dn = dinv[n];
  float s = dn * xw[(size_t)n * DD + c];
  int e0 = offs[n], e1 = offs[n + 1];
  for (int e = e0; e < e1; ++e) {
    int src = lists[e];
    s += dinv[src] * xw[(size_t)src * DD + c];
  }
  float v = dn * s + bias[c];
  out[(size_t)n * DD + c] = fmaxf(v, 0.f);
}

// ---------------- generic fp32 GEMM: C = A[M,K]@B[K,N] (+bias)(+resid)(relu) ----------------
__global__ __launch_bounds__(256) void gemm_kernel(
    const float* __restrict__ A, const float* __restrict__ Bm, float* __restrict__ C,
    int N, int Kd, const float* __restrict__ bias,
    const float* __restrict__ resid, int relu) {
  __shared__ float As[64][36];   // pad 36 -> 16B-aligned rows, 2-way-max conflicts
  __shared__ float Bs[32][64];
  int tid = threadIdx.x;
  int m0 = blockIdx.y * 64, n0 = blockIdx.x * 64;
  int ty = tid >> 4, tx = tid & 15;
  float acc[4][4] = {};
  for (int k0 = 0; k0 < Kd; k0 += 32) {
    {
      int row = tid >> 2, kc = (tid & 3) * 8;
      const float* ap = A + (size_t)(m0 + row) * Kd + k0 + kc;
      float4 v0 = *(const float4*)ap;
      float4 v1 = *(const float4*)(ap + 4);
      *(float4*)&As[row][kc]     = v0;
      *(float4*)&As[row][kc + 4] = v1;
      int brow = tid >> 3, nc = (tid & 7) * 8;
      const float* bp = Bm + (size_t)(k0 + brow) * N + n0 + nc;
      float4 w0 = *(const float4*)bp;
      float4 w1 = *(const float4*)(bp + 4);
      *(float4*)&Bs[brow][nc]     = w0;
      *(float4*)&Bs[brow][nc + 4] = w1;
    }
    __syncthreads();
    #pragma unroll
    for (int kk = 0; kk < 32; ++kk) {
      float a0 = As[ty * 4 + 0][kk];
      float a1 = As[ty * 4 + 1][kk];
      float a2 = As[ty * 4 + 2][kk];
      float a3 = As[ty * 4 + 3][kk];
      float4 b4 = *(const float4*)&Bs[kk][tx * 4];
      acc[0][0] += a0 * b4.x; acc[0][1] += a0 * b4.y; acc[0][2] += a0 * b4.z; acc[0][3] += a0 * b4.w;
      acc[1][0] += a1 * b4.x; acc[1][1] += a1 * b4.y; acc[1][2] += a1 * b4.z; acc[1][3] += a1 * b4.w;
      acc[2][0] += a2 * b4.x; acc[2][1] += a2 * b4.y; acc[2][2] += a2 * b4.z; acc[2][3] += a2 * b4.w;
      acc[3][0] += a3 * b4.x; acc[3][1] += a3 * b4.y; acc[3][2] += a3 * b4.z; acc[3][3] += a3 * b4.w;
    }
    __syncthreads();
  }
  #pragma unroll
  for (int i = 0; i < 4; ++i) {
    int r = m0 + ty * 4 + i;
    int cpos = n0 + tx * 4;
    float4 v = make_float4(acc[i][0], acc[i][1], acc[i][2], acc[i][3]);
    if (bias) {
      float4 bv = *(const float4*)&bias[cpos];
      v.x += bv.x; v.y += bv.y; v.z += bv.z; v.w += bv.w;
    }
    if (resid) {
      float4 rv = *(const float4*)&resid[(size_t)r * N + cpos];
      v.x += rv.x; v.y += rv.y; v.z += rv.z; v.w += rv.w;
    }
    if (relu) {
      v.x = fmaxf(v.x, 0.f); v.y = fmaxf(v.y, 0.f);
      v.z = fmaxf(v.z, 0.f); v.w = fmaxf(v.w, 0.f);
    }
    *(float4*)&C[(size_t)r * N + cpos] = v;
  }
}

// ---------------- fused attention (online softmax), dh=16, full 512 keys ----------------
// LDS rows skewed by 8 floats per 64 rows so the 4 p-groups hit distinct banks.
#define KS(arr, r, j) arr[((r) << 4) + (((r) >> 6) << 3) + (j)]
__global__ __launch_bounds__(256) void attn_kernel(
    const float* __restrict__ qh, const float* __restrict__ kh,
    const float* __restrict__ vh, float* __restrict__ out) {
  __shared__ float ks[256 * 16 + 24];
  __shared__ float vs[256 * 16 + 24];
  int bx = blockIdx.x;
  int qc = bx & 7;
  int h  = (bx >> 3) & 7;
  int b  = bx >> 6;
  int tid = threadIdx.x;
  int r = tid >> 2;       // q row in chunk (0..63)
  int p = tid & 3;        // key partition
  int qrow = b * MM + qc * 64 + r;
  float qv[16];
  const float* qp = qh + (size_t)qrow * DD + h * DHH;
  #pragma unroll
  for (int j = 0; j < 16; ++j) qv[j] = qp[j];
  float mval = -1e30f, l = 0.f;
  float o[16];
  #pragma unroll
  for (int j = 0; j < 16; ++j) o[j] = 0.f;
  for (int ch = 0; ch < 2; ++ch) {
    __syncthreads();
    for (int idx = tid; idx < 256 * 4; idx += 256) {
      int row = idx >> 2, seg = idx & 3;
      int krow = b * MM + ch * 256 + row;
      *(float4*)&KS(ks, row, seg * 4) = *(const float4*)&kh[(size_t)krow * DD + h * DHH + seg * 4];
      *(float4*)&KS(vs, row, seg * 4) = *(const float4*)&vh[(size_t)krow * DD + h * DHH + seg * 4];
    }
    __syncthreads();
    for (int kk = p * 64; kk < p * 64 + 64; ++kk) {
      float s = 0.f;
      #pragma unroll
      for (int j = 0; j < 16; ++j) s += qv[j] * KS(ks, kk, j);
      s *= 0.25f;                              // 1/sqrt(16)
      float nm = fmaxf(mval, s);
      float scale = __expf(mval - nm);
      float pw = __expf(s - nm);
      l = l * scale + pw;
      #pragma unroll
      for (int j = 0; j < 16; ++j) o[j] = o[j] * scale + pw * KS(vs, kk, j);
      mval = nm;
    }
  }
  // merge 4 partitions (lanes r*4 .. r*4+3)
  #pragma unroll
  for (int off = 1; off <= 2; off <<= 1) {
    float m2 = __shfl_xor(mval, off);
    float l2 = __shfl_xor(l, off);
    float nm = fmaxf(mval, m2);
    float s1 = __expf(mval - nm), s2 = __expf(m2 - nm);
    l = l * s1 + l2 * s2;
    #pragma unroll
    for (int j = 0; j < 16; ++j) {
      float o2 = __shfl_xor(o[j], off);
      o[j] = o[j] * s1 + o2 * s2;
    }
    mval = nm;
  }
  if (p == 0) {
    float invl = 1.f / l;
    float* op = out + (size_t)qrow * DD + h * DHH;
    #pragma unroll
    for (int j = 0; j < 16; ++j) op[j] = o[j] * invl;
  }
}

// ---------------- layernorm over D=128: y = (x-mu)*rsqrt(var+1e-5)*g + b ----------------
__global__ void ln_kernel(const float* __restrict__ x, const float* __restrict__ g,
                          const float* __restrict__ bb, float* __restrict__ out) {
  int row = blockIdx.x * 4 + (threadIdx.x >> 6);
  int lane = threadIdx.x & 63;
  float2 xv = *(const float2*)&x[(size_t)row * DD + lane * 2];
  float s = xv.x + xv.y;
  #pragma unroll
  for (int off = 1; off < 64; off <<= 1) s += __shfl_xor(s, off);
  float mu = s * (1.f / 128.f);
  float d0 = xv.x - mu, d1 = xv.y - mu;
  float sq = d0 * d0 + d1 * d1;
  #pragma unroll
  for (int off = 1; off < 64; off <<= 1) sq += __shfl_xor(sq, off);
  float rs = rsqrtf(sq * (1.f / 128.f) + 1e-5f);
  float2 gg = *(const float2*)&g[lane * 2];
  float2 bv = *(const float2*)&bb[lane * 2];
  float2 y;
  y.x = d0 * rs * gg.x + bv.x;
  y.y = d1 * rs * gg.y + bv.y;
  *(float2*)&out[(size_t)row * DD + lane * 2] = y;
}

extern "C" void kernel_launch(void* const* d_in, const int* in_sizes, int n_in,
                              void* d_out, int out_size, void* d_ws, size_t ws_size,
                              hipStream_t stream) {
  (void)in_sizes; (void)n_in; (void)out_size; (void)ws_size;
  const float* enc  = (const float*)d_in[0];
  const float* xenc = (const float*)d_in[1];
  const float* gw1  = (const float*)d_in[2];
  const float* gb1  = (const float*)d_in[3];
  const float* gw2  = (const float*)d_in[4];
  const float* gb2  = (const float*)d_in[5];
  const float* Wq   = (const float*)d_in[6];
  const float* Wk   = (const float*)d_in[7];
  const float* Wv   = (const float*)d_in[8];
  const float* Wo   = (const float*)d_in[9];
  const float* ln1g = (const float*)d_in[10];
  const float* ln1b = (const float*)d_in[11];
  const float* W1   = (const float*)d_in[12];
  const float* b1   = (const float*)d_in[13];
  const float* W2   = (const float*)d_in[14];
  const float* b2   = (const float*)d_in[15];
  const float* ln2g = (const float*)d_in[16];
  const float* ln2b = (const float*)d_in[17];
  float* outp = (float*)d_out;

  char* w = (char*)d_ws;
  auto alloc = [&](size_t bytes) -> char* {
    char* p = w;
    w += (bytes + 255) & ~(size_t)255;
    return p;
  };
  float* mu    = (float*)alloc((size_t)NNODE * 4);
  float* rstd  = (float*)alloc((size_t)NNODE * 4);
  float* dinv  = (float*)alloc((size_t)NNODE * 4);
  int*   nb    = (int*)  alloc((size_t)NEDGE * 4);
  int*   cnt   = (int*)  alloc((size_t)NNODE * 4);
  int*   offs  = (int*)  alloc((size_t)(NNODE + 1) * 4);
  int*   curs  = (int*)  alloc((size_t)NNODE * 4);
  int*   lists = (int*)  alloc((size_t)NEDGE * 4);
  float* gram  = (float*)alloc((size_t)BB * MM * MM * 4);        // 16 MB, reused
  float* kvb   = (float*)alloc((size_t)NNODE * DD * 4);          // GCN output, persists
  float* bufx  = (float*)alloc((size_t)NNODE * DD * 4);
  float* bufxl = (float*)alloc((size_t)NNODE * DD * 4);
  float* bufh  = (float*)alloc((size_t)NNODE * DD * 4);
  float* bufh1 = (float*)alloc((size_t)NNODE * DD * 4);
  float* SA = gram;
  float* SB = gram + (size_t)1048576;
  float* SC = gram + (size_t)2097152;
  float* SD = gram + (size_t)3145728;

  auto gemm = [&](const float* A, const float* Bm, float* C, int Mr, int N, int Kd,
                  const float* bias, const float* resid, int relu) {
    dim3 g(N / 64, Mr / 64);
    gemm_kernel<<<g, 256, 0, stream>>>(A, Bm, C, N, Kd, bias, resid, relu);
  };

  // ---- graph build ----
  colmean_kernel<<<NNODE / 256, 256, 0, stream>>>(xenc, mu);
  gram_kernel<<<dim3(36, BB), 256, 0, stream>>>(xenc, gram);
  rstd_kernel<<<NNODE / 256, 256, 0, stream>>>(gram, mu, rstd);
  select_kernel<<<NNODE / 4, 256, 0, stream>>>(gram, mu, rstd, nb);
  hipMemsetAsync(cnt, 0, (size_t)NNODE * 4, stream);
  count_kernel<<<NEDGE / 256, 256, 0, stream>>>(nb, cnt);
  scan_kernel<<<1, 256, 0, stream>>>(cnt, offs, curs, dinv);
  scatter_kernel<<<NEDGE / 256, 256, 0, stream>>>(nb, curs, lists);

  // ---- 2-layer GCN ----
  gemm(enc, gw1, SA, NNODE, DD, DD, nullptr, nullptr, 0);          // xw1
  agg_kernel<<<NNODE / 2, 256, 0, stream>>>(SA, dinv, offs, lists, gb1, SB);  // x1
  gemm(SB, gw2, SC, NNODE, DD, DD, nullptr, nullptr, 0);           // xw2
  agg_kernel<<<NNODE / 2, 256, 0, stream>>>(SC, dinv, offs, lists, gb2, kvb); // kv

  // ---- transformer encoder layers ----
  for (int l = 0; l < 2; ++l) {
    const float* hq = (l == 0) ? enc : bufh1;
    const float* Wql = Wq + (size_t)l * DD * DD;
    const float* Wkl = Wk + (size_t)l * DD * DD;
    const float* Wvl = Wv + (size_t)l * DD * DD;
    const float* Wol = Wo + (size_t)l * DD * DD;
    gemm(hq,  Wql, SA, NNODE, DD, DD, nullptr, nullptr, 0);        // qh
    gemm(kvb, Wkl, SB, NNODE, DD, DD, nullptr, nullptr, 0);        // kh
    gemm(kvb, Wvl, SC, NNODE, DD, DD, nullptr, nullptr, 0);        // vh
    attn_kernel<<<BB * HH * 8, 256, 0, stream>>>(SA, SB, SC, SD);  // attno
    gemm(SD, Wol, bufx, NNODE, DD, DD, nullptr, hq, 0);            // q + o@Wo
    ln_kernel<<<NNODE / 4, 256, 0, stream>>>(bufx, ln1g + l * DD, ln1b + l * DD, bufxl);
    gemm(bufxl, W1 + (size_t)l * DD * NDFF, gram, NNODE, NDFF, DD,
         b1 + l * NDFF, nullptr, 1);                               // relu(x@W1+b1), 16MB
    gemm(gram, W2 + (size_t)l * NDFF * DD, bufh, NNODE, DD, NDFF,
         b2 + l * DD, bufxl, 0);                                   // x + ff@W2+b2
    ln_kernel<<<NNODE / 4, 256, 0, stream>>>(bufh, ln2g + l * DD, ln2b + l * DD,
                                             (l == 1) ? outp : bufh1);
  }
}

// Round 2
// 512.887 us; speedup vs baseline: 1.1360x; 1.1360x over previous
//
#include <hip/hip_runtime.h>
#include <math.h>

#define BB 16
#define MM 512
#define LL 1024
#define DD 128
#define KK 16
#define HH 8
#define DHH 16
#define NDFF 512
#define NNODE (BB*MM)      // 8192
#define NEDGE (NNODE*KK)   // 131072

// ---------------- column partial sums over L-chunks: part[chunk, bm] ----------------
// grid (32, 8): x covers 256 columns (bm chunk), y covers 128 consecutive l rows.
__global__ void colmean_part_kernel(const float* __restrict__ X, float* __restrict__ part) {
  int bm = blockIdx.x * 256 + threadIdx.x;          // 0..8191
  int b = bm >> 9, m = bm & (MM - 1);
  int l0 = blockIdx.y * 128;
  const float* p = X + (size_t)b * LL * MM + (size_t)l0 * MM + m;
  float s = 0.f;
  #pragma unroll 8
  for (int l = 0; l < 128; ++l) s += p[(size_t)l * MM];
  part[(size_t)blockIdx.y * NNODE + bm] = s;
}

__global__ void colmean_finish_kernel(const float* __restrict__ part, float* __restrict__ mu) {
  int bm = blockIdx.x * 256 + threadIdx.x;
  float s = 0.f;
  #pragma unroll
  for (int j = 0; j < 8; ++j) s += part[(size_t)j * NNODE + bm];
  mu[bm] = s * (1.f / 1024.f);
}

// ---------------- raw Gram G = X^T X per batch, symmetric tile pairs ----------------
__global__ __launch_bounds__(256) void gram_kernel(const float* __restrict__ X,
                                                   float* __restrict__ G) {
  int b = blockIdx.y;
  int pi = blockIdx.x;                 // 0..35 upper-triangular tile pairs (8x8 tiles)
  int ti = 0, rem = pi;
  while (rem >= 8 - ti) { rem -= 8 - ti; ++ti; }
  int tj = ti + rem;
  int m0 = ti * 64, n0 = tj * 64;
  __shared__ float As[32][64];
  __shared__ float Bs[32][64];
  int tid = threadIdx.x;
  int ty = tid >> 4, tx = tid & 15;
  float acc[4][4] = {};
  const float* Xb = X + (size_t)b * LL * MM;
  for (int l0 = 0; l0 < LL; l0 += 32) {
    int rr = tid >> 3, cc = (tid & 7) * 8;
    const float* p = Xb + (size_t)(l0 + rr) * MM + m0 + cc;
    const float* q = Xb + (size_t)(l0 + rr) * MM + n0 + cc;
    float4 a0 = *(const float4*)p;
    float4 a1 = *(const float4*)(p + 4);
    float4 c0 = *(const float4*)q;
    float4 c1 = *(const float4*)(q + 4);
    *(float4*)&As[rr][cc]     = a0;
    *(float4*)&As[rr][cc + 4] = a1;
    *(float4*)&Bs[rr][cc]     = c0;
    *(float4*)&Bs[rr][cc + 4] = c1;
    __syncthreads();
    #pragma unroll
    for (int kk = 0; kk < 32; ++kk) {
      float4 a4 = *(const float4*)&As[kk][ty * 4];
      float4 b4 = *(const float4*)&Bs[kk][tx * 4];
      acc[0][0] += a4.x * b4.x; acc[0][1] += a4.x * b4.y; acc[0][2] += a4.x * b4.z; acc[0][3] += a4.x * b4.w;
      acc[1][0] += a4.y * b4.x; acc[1][1] += a4.y * b4.y; acc[1][2] += a4.y * b4.z; acc[1][3] += a4.y * b4.w;
      acc[2][0] += a4.z * b4.x; acc[2][1] += a4.z * b4.y; acc[2][2] += a4.z * b4.z; acc[2][3] += a4.z * b4.w;
      acc[3][0] += a4.w * b4.x; acc[3][1] += a4.w * b4.y; acc[3][2] += a4.w * b4.z; acc[3][3] += a4.w * b4.w;
    }
    __syncthreads();
  }
  float* Gb = G + (size_t)b * MM * MM;
  #pragma unroll
  for (int i = 0; i < 4; ++i) {
    #pragma unroll
    for (int j = 0; j < 4; ++j) {
      int r = m0 + ty * 4 + i, c = n0 + tx * 4 + j;
      Gb[(size_t)r * MM + c] = acc[i][j];
      if (ti != tj) Gb[(size_t)c * MM + r] = acc[i][j];
    }
  }
}

// ---------------- rstd[b,m] = 1/std (std==0 -> 1) ----------------
__global__ void rstd_kernel(const float* __restrict__ G, const float* __restrict__ mu,
                            float* __restrict__ rstd) {
  int bm = blockIdx.x * 256 + threadIdx.x;
  int b = bm >> 9, m = bm & (MM - 1);
  float g = G[(size_t)b * MM * MM + (size_t)m * MM + m];
  float mm = mu[bm];
  float cov = (g - 1024.f * mm * mm) * (1.f / 1023.f);
  float sd = sqrtf(fmaxf(cov, 0.f));
  rstd[bm] = (sd == 0.f) ? 1.f : (1.f / sd);
}

// ---------------- neighbors: ascending stable argsort positions 1..16 ----------------
__global__ void select_kernel(const float* __restrict__ G, const float* __restrict__ mu,
                              const float* __restrict__ rstd, int* __restrict__ nb) {
  int w = threadIdx.x >> 6, lane = threadIdx.x & 63;
  int bm = blockIdx.x * 4 + w;
  int b = bm >> 9, m = bm & (MM - 1);
  const float* Gr = G + (size_t)b * MM * MM + (size_t)m * MM;
  const float* mub = mu + b * MM;
  const float* rsb = rstd + b * MM;
  float mm = mub[m], rm = rsb[m];
  float vals[8];
  int excl = 0;
  #pragma unroll
  for (int j = 0; j < 8; ++j) {
    int n = lane + j * 64;
    float cov = (Gr[n] - 1024.f * mm * mub[n]) * (1.f / 1023.f);
    vals[j] = cov * rm * rsb[n];
  }
  int* out = nb + (size_t)bm * KK;
  for (int it = 0; it < KK + 1; ++it) {
    float bv = 1e30f; int bi = 1 << 30;
    #pragma unroll
    for (int j = 0; j < 8; ++j) {
      if (!((excl >> j) & 1)) {
        int n = lane + j * 64;
        if (vals[j] < bv) { bv = vals[j]; bi = n; }   // strict < keeps smaller n on ties
      }
    }
    for (int off = 32; off; off >>= 1) {
      float v2 = __shfl_down(bv, off);
      int   i2 = __shfl_down(bi, off);
      if (v2 < bv || (v2 == bv && i2 < bi)) { bv = v2; bi = i2; }
    }
    bi = __shfl(bi, 0);
    if ((bi & 63) == lane) excl |= 1 << (bi >> 6);
    if (it > 0 && lane == 0) out[it - 1] = bi;
  }
}

// ---------------- degree counts (without self-loop) ----------------
__global__ void count_kernel(const int* __restrict__ nb, int* __restrict__ cnt) {
  int e = blockIdx.x * 256 + threadIdx.x;           // < NEDGE
  int b = e >> 13, i = e & 8191;
  int dst = b * MM + nb[(size_t)b * 8192 + i];
  atomicAdd(&cnt[dst], 1);
}

// ---------------- exclusive scan + cursor + dinv (single block) ----------------
__global__ void scan_kernel(const int* __restrict__ cnt, int* __restrict__ offs,
                            int* __restrict__ curs, float* __restrict__ dinv) {
  __shared__ int part[256];
  int tid = threadIdx.x;
  int base = tid * 32;
  int local[32];
  int s = 0;
  #pragma unroll
  for (int i = 0; i < 32; ++i) { local[i] = cnt[base + i]; s += local[i]; }
  part[tid] = s;
  __syncthreads();
  for (int off = 1; off < 256; off <<= 1) {
    int v = (tid >= off) ? part[tid - off] : 0;
    __syncthreads();
    part[tid] += v;
    __syncthreads();
  }
  int run = part[tid] - s;   // exclusive base of this chunk
  #pragma unroll
  for (int i = 0; i < 32; ++i) {
    int n = base + i;
    offs[n] = run; curs[n] = run;
    run += local[i];
    dinv[n] = rsqrtf((float)(local[i] + 1));   // +1 = self loop
  }
  if (tid == 255) offs[NNODE] = run;
}

// ---------------- scatter reverse edge lists ----------------
__global__ void scatter_kernel(const int* __restrict__ nb, int* __restrict__ curs,
                               int* __restrict__ lists) {
  int e = blockIdx.x * 256 + threadIdx.x;
  int b = e >> 13, i = e & 8191;
  int dst = b * MM + nb[(size_t)b * 8192 + i];
  int src = b * MM + (i & (MM - 1));
  int pos = atomicAdd(&curs[dst], 1);
  lists[pos] = src;
}

// ---------------- GCN aggregation ----------------
__global__ void agg_kernel(const float* __restrict__ xw, const float* __restrict__ dinv,
                           const int* __restrict__ offs, const int* __restrict__ lists,
                           const float* __restrict__ bias, float* __restrict__ out) {
  int n = blockIdx.x * 2 + (threadIdx.x >> 7);
  int c = threadIdx.x & 127;
  float dn = dinv[n];
  float s = dn * xw[(size_t)n * DD + c];
  int e0 = offs[n], e1 = offs[n + 1];
  for (int e = e0; e < e1; ++e) {
    int src = lists[e];
    s += dinv[src] * xw[(size_t)src * DD + c];
  }
  float v = dn * s + bias[c];
  out[(size_t)n * DD + c] = fmaxf(v, 0.f);
}

// ---------------- generic fp32 GEMM: C = A[M,K]@B[K,N] (+bias)(+resid)(relu) ----------------
__global__ __launch_bounds__(256) void gemm_kernel(
    const float* __restrict__ A, const float* __restrict__ Bm, float* __restrict__ C,
    int N, int Kd, const float* __restrict__ bias,
    const float* __restrict__ resid, int relu) {
  __shared__ float As[64][36];
  __shared__ float Bs[32][64];
  int tid = threadIdx.x;
  int m0 = blockIdx.y * 64, n0 = blockIdx.x * 64;
  int ty = tid >> 4, tx = tid & 15;
  float acc[4][4] = {};
  for (int k0 = 0; k0 < Kd; k0 += 32) {
    {
      int row = tid >> 2, kc = (tid & 3) * 8;
      const float* ap = A + (size_t)(m0 + row) * Kd + k0 + kc;
      float4 v0 = *(const float4*)ap;
      float4 v1 = *(const float4*)(ap + 4);
      *(float4*)&As[row][kc]     = v0;
      *(float4*)&As[row][kc + 4] = v1;
      int brow = tid >> 3, nc = (tid & 7) * 8;
      const float* bp = Bm + (size_t)(k0 + brow) * N + n0 + nc;
      float4 w0 = *(const float4*)bp;
      float4 w1 = *(const float4*)(bp + 4);
      *(float4*)&Bs[brow][nc]     = w0;
      *(float4*)&Bs[brow][nc + 4] = w1;
    }
    __syncthreads();
    #pragma unroll
    for (int kk = 0; kk < 32; ++kk) {
      float a0 = As[ty * 4 + 0][kk];
      float a1 = As[ty * 4 + 1][kk];
      float a2 = As[ty * 4 + 2][kk];
      float a3 = As[ty * 4 + 3][kk];
      float4 b4 = *(const float4*)&Bs[kk][tx * 4];
      acc[0][0] += a0 * b4.x; acc[0][1] += a0 * b4.y; acc[0][2] += a0 * b4.z; acc[0][3] += a0 * b4.w;
      acc[1][0] += a1 * b4.x; acc[1][1] += a1 * b4.y; acc[1][2] += a1 * b4.z; acc[1][3] += a1 * b4.w;
      acc[2][0] += a2 * b4.x; acc[2][1] += a2 * b4.y; acc[2][2] += a2 * b4.z; acc[2][3] += a2 * b4.w;
      acc[3][0] += a3 * b4.x; acc[3][1] += a3 * b4.y; acc[3][2] += a3 * b4.z; acc[3][3] += a3 * b4.w;
    }
    __syncthreads();
  }
  #pragma unroll
  for (int i = 0; i < 4; ++i) {
    int r = m0 + ty * 4 + i;
    int cpos = n0 + tx * 4;
    float4 v = make_float4(acc[i][0], acc[i][1], acc[i][2], acc[i][3]);
    if (bias) {
      float4 bv = *(const float4*)&bias[cpos];
      v.x += bv.x; v.y += bv.y; v.z += bv.z; v.w += bv.w;
    }
    if (resid) {
      float4 rv = *(const float4*)&resid[(size_t)r * N + cpos];
      v.x += rv.x; v.y += rv.y; v.z += rv.z; v.w += rv.w;
    }
    if (relu) {
      v.x = fmaxf(v.x, 0.f); v.y = fmaxf(v.y, 0.f);
      v.z = fmaxf(v.z, 0.f); v.w = fmaxf(v.w, 0.f);
    }
    *(float4*)&C[(size_t)r * N + cpos] = v;
  }
}

// ---------------- fused attention (online softmax), dh=16, full 512 keys ----------------
#define KS(arr, r, j) arr[((r) << 4) + (((r) >> 6) << 3) + (j)]
__global__ __launch_bounds__(256) void attn_kernel(
    const float* __restrict__ qh, const float* __restrict__ kh,
    const float* __restrict__ vh, float* __restrict__ out) {
  __shared__ float ks[256 * 16 + 24];
  __shared__ float vs[256 * 16 + 24];
  int bx = blockIdx.x;
  int qc = bx & 7;
  int h  = (bx >> 3) & 7;
  int b  = bx >> 6;
  int tid = threadIdx.x;
  int r = tid >> 2;
  int p = tid & 3;
  int qrow = b * MM + qc * 64 + r;
  float qv[16];
  const float* qp = qh + (size_t)qrow * DD + h * DHH;
  #pragma unroll
  for (int j = 0; j < 16; ++j) qv[j] = qp[j];
  float mval = -1e30f, l = 0.f;
  float o[16];
  #pragma unroll
  for (int j = 0; j < 16; ++j) o[j] = 0.f;
  for (int ch = 0; ch < 2; ++ch) {
    __syncthreads();
    for (int idx = tid; idx < 256 * 4; idx += 256) {
      int row = idx >> 2, seg = idx & 3;
      int krow = b * MM + ch * 256 + row;
      *(float4*)&KS(ks, row, seg * 4) = *(const float4*)&kh[(size_t)krow * DD + h * DHH + seg * 4];
      *(float4*)&KS(vs, row, seg * 4) = *(const float4*)&vh[(size_t)krow * DD + h * DHH + seg * 4];
    }
    __syncthreads();
    for (int kk = p * 64; kk < p * 64 + 64; ++kk) {
      float s = 0.f;
      #pragma unroll
      for (int j = 0; j < 16; ++j) s += qv[j] * KS(ks, kk, j);
      s *= 0.25f;
      float nm = fmaxf(mval, s);
      float scale = __expf(mval - nm);
      float pw = __expf(s - nm);
      l = l * scale + pw;
      #pragma unroll
      for (int j = 0; j < 16; ++j) o[j] = o[j] * scale + pw * KS(vs, kk, j);
      mval = nm;
    }
  }
  #pragma unroll
  for (int off = 1; off <= 2; off <<= 1) {
    float m2 = __shfl_xor(mval, off);
    float l2 = __shfl_xor(l, off);
    float nm = fmaxf(mval, m2);
    float s1 = __expf(mval - nm), s2 = __expf(m2 - nm);
    l = l * s1 + l2 * s2;
    #pragma unroll
    for (int j = 0; j < 16; ++j) {
      float o2 = __shfl_xor(o[j], off);
      o[j] = o[j] * s1 + o2 * s2;
    }
    mval = nm;
  }
  if (p == 0) {
    float invl = 1.f / l;
    float* op = out + (size_t)qrow * DD + h * DHH;
    #pragma unroll
    for (int j = 0; j < 16; ++j) op[j] = o[j] * invl;
  }
}

// ---------------- layernorm over D=128 ----------------
__global__ void ln_kernel(const float* __restrict__ x, const float* __restrict__ g,
                          const float* __restrict__ bb, float* __restrict__ out) {
  int row = blockIdx.x * 4 + (threadIdx.x >> 6);
  int lane = threadIdx.x & 63;
  float2 xv = *(const float2*)&x[(size_t)row * DD + lane * 2];
  float s = xv.x + xv.y;
  #pragma unroll
  for (int off = 1; off < 64; off <<= 1) s += __shfl_xor(s, off);
  float mu = s * (1.f / 128.f);
  float d0 = xv.x - mu, d1 = xv.y - mu;
  float sq = d0 * d0 + d1 * d1;
  #pragma unroll
  for (int off = 1; off < 64; off <<= 1) sq += __shfl_xor(sq, off);
  float rs = rsqrtf(sq * (1.f / 128.f) + 1e-5f);
  float2 gg = *(const float2*)&g[lane * 2];
  float2 bv = *(const float2*)&bb[lane * 2];
  float2 y;
  y.x = d0 * rs * gg.x + bv.x;
  y.y = d1 * rs * gg.y + bv.y;
  *(float2*)&out[(size_t)row * DD + lane * 2] = y;
}

extern "C" void kernel_launch(void* const* d_in, const int* in_sizes, int n_in,
                              void* d_out, int out_size, void* d_ws, size_t ws_size,
                              hipStream_t stream) {
  (void)in_sizes; (void)n_in; (void)out_size; (void)ws_size;
  const float* enc  = (const float*)d_in[0];
  const float* xenc = (const float*)d_in[1];
  const float* gw1  = (const float*)d_in[2];
  const float* gb1  = (const float*)d_in[3];
  const float* gw2  = (const float*)d_in[4];
  const float* gb2  = (const float*)d_in[5];
  const float* Wq   = (const float*)d_in[6];
  const float* Wk   = (const float*)d_in[7];
  const float* Wv   = (const float*)d_in[8];
  const float* Wo   = (const float*)d_in[9];
  const float* ln1g = (const float*)d_in[10];
  const float* ln1b = (const float*)d_in[11];
  const float* W1   = (const float*)d_in[12];
  const float* b1   = (const float*)d_in[13];
  const float* W2   = (const float*)d_in[14];
  const float* b2   = (const float*)d_in[15];
  const float* ln2g = (const float*)d_in[16];
  const float* ln2b = (const float*)d_in[17];
  float* outp = (float*)d_out;

  char* w = (char*)d_ws;
  auto alloc = [&](size_t bytes) -> char* {
    char* p = w;
    w += (bytes + 255) & ~(size_t)255;
    return p;
  };
  float* mu    = (float*)alloc((size_t)NNODE * 4);
  float* rstd  = (float*)alloc((size_t)NNODE * 4);
  float* dinv  = (float*)alloc((size_t)NNODE * 4);
  float* mpart = (float*)alloc((size_t)8 * NNODE * 4);
  int*   nb    = (int*)  alloc((size_t)NEDGE * 4);
  int*   cnt   = (int*)  alloc((size_t)NNODE * 4);
  int*   offs  = (int*)  alloc((size_t)(NNODE + 1) * 4);
  int*   curs  = (int*)  alloc((size_t)NNODE * 4);
  int*   lists = (int*)  alloc((size_t)NEDGE * 4);
  float* gram  = (float*)alloc((size_t)BB * MM * MM * 4);        // 16 MB, reused
  float* kvb   = (float*)alloc((size_t)NNODE * DD * 4);
  float* bufx  = (float*)alloc((size_t)NNODE * DD * 4);
  float* bufxl = (float*)alloc((size_t)NNODE * DD * 4);
  float* bufh  = (float*)alloc((size_t)NNODE * DD * 4);
  float* bufh1 = (float*)alloc((size_t)NNODE * DD * 4);
  float* SA = gram;
  float* SB = gram + (size_t)1048576;
  float* SC = gram + (size_t)2097152;
  float* SD = gram + (size_t)3145728;

  auto gemm = [&](const float* A, const float* Bm, float* C, int Mr, int N, int Kd,
                  const float* bias, const float* resid, int relu) {
    dim3 g(N / 64, Mr / 64);
    gemm_kernel<<<g, 256, 0, stream>>>(A, Bm, C, N, Kd, bias, resid, relu);
  };

  // ---- graph build ----
  colmean_part_kernel<<<dim3(32, 8), 256, 0, stream>>>(xenc, mpart);
  colmean_finish_kernel<<<NNODE / 256, 256, 0, stream>>>(mpart, mu);
  gram_kernel<<<dim3(36, BB), 256, 0, stream>>>(xenc, gram);
  rstd_kernel<<<NNODE / 256, 256, 0, stream>>>(gram, mu, rstd);
  select_kernel<<<NNODE / 4, 256, 0, stream>>>(gram, mu, rstd, nb);
  hipMemsetAsync(cnt, 0, (size_t)NNODE * 4, stream);
  count_kernel<<<NEDGE / 256, 256, 0, stream>>>(nb, cnt);
  scan_kernel<<<1, 256, 0, stream>>>(cnt, offs, curs, dinv);
  scatter_kernel<<<NEDGE / 256, 256, 0, stream>>>(nb, curs, lists);

  // ---- 2-layer GCN ----
  gemm(enc, gw1, SA, NNODE, DD, DD, nullptr, nullptr, 0);
  agg_kernel<<<NNODE / 2, 256, 0, stream>>>(SA, dinv, offs, lists, gb1, SB);
  gemm(SB, gw2, SC, NNODE, DD, DD, nullptr, nullptr, 0);
  agg_kernel<<<NNODE / 2, 256, 0, stream>>>(SC, dinv, offs, lists, gb2, kvb);

  // ---- transformer encoder layers ----
  for (int l = 0; l < 2; ++l) {
    const float* hq = (l == 0) ? enc : bufh1;
    const float* Wql = Wq + (size_t)l * DD * DD;
    const float* Wkl = Wk + (size_t)l * DD * DD;
    const float* Wvl = Wv + (size_t)l * DD * DD;
    const float* Wol = Wo + (size_t)l * DD * DD;
    gemm(hq,  Wql, SA, NNODE, DD, DD, nullptr, nullptr, 0);
    gemm(kvb, Wkl, SB, NNODE, DD, DD, nullptr, nullptr, 0);
    gemm(kvb, Wvl, SC, NNODE, DD, DD, nullptr, nullptr, 0);
    attn_kernel<<<BB * HH * 8, 256, 0, stream>>>(SA, SB, SC, SD);
    gemm(SD, Wol, bufx, NNODE, DD, DD, nullptr, hq, 0);
    ln_kernel<<<NNODE / 4, 256, 0, stream>>>(bufx, ln1g + l * DD, ln1b + l * DD, bufxl);
    gemm(bufxl, W1 + (size_t)l * DD * NDFF, gram, NNODE, NDFF, DD,
         b1 + l * NDFF, nullptr, 1);
    gemm(gram, W2 + (size_t)l * NDFF * DD, bufh, NNODE, DD, NDFF,
         b2 + l * DD, bufxl, 0);
    ln_kernel<<<NNODE / 4, 256, 0, stream>>>(bufh, ln2g + l * DD, ln2b + l * DD,
                                             (l == 1) ? outp : bufh1);
  }
}

// Round 3
// 487.240 us; speedup vs baseline: 1.1958x; 1.0526x over previous
//
#include <hip/hip_runtime.h>
#include <math.h>

#define BB 16
#define MM 512
#define LL 1024
#define DD 128
#define KK 16
#define HH 8
#define DHH 16
#define NDFF 512
#define NNODE (BB*MM)      // 8192
#define NEDGE (NNODE*KK)   // 131072

// ---------------- column partial sums over L-chunks: part[chunk, bm] ----------------
__global__ void colmean_part_kernel(const float* __restrict__ X, float* __restrict__ part) {
  int bm = blockIdx.x * 256 + threadIdx.x;          // 0..8191
  int b = bm >> 9, m = bm & (MM - 1);
  int l0 = blockIdx.y * 128;
  const float* p = X + (size_t)b * LL * MM + (size_t)l0 * MM + m;
  float s = 0.f;
  #pragma unroll 8
  for (int l = 0; l < 128; ++l) s += p[(size_t)l * MM];
  part[(size_t)blockIdx.y * NNODE + bm] = s;
}

__global__ void colmean_finish_kernel(const float* __restrict__ part, float* __restrict__ mu) {
  int bm = blockIdx.x * 256 + threadIdx.x;
  float s = 0.f;
  #pragma unroll
  for (int j = 0; j < 8; ++j) s += part[(size_t)j * NNODE + bm];
  mu[bm] = s * (1.f / 1024.f);
}

// ---------------- raw Gram partials: G_z = sum over half-L of X^T X ----------------
// grid (36, BB, 2): z selects L-half and partial buffer. 1152 blocks.
__global__ __launch_bounds__(256) void gram_kernel(const float* __restrict__ X,
                                                   float* __restrict__ G0,
                                                   float* __restrict__ G1) {
  int b = blockIdx.y;
  int z = blockIdx.z;
  float* G = z ? G1 : G0;
  int pi = blockIdx.x;                 // 0..35 upper-triangular tile pairs (8x8 tiles)
  int ti = 0, rem = pi;
  while (rem >= 8 - ti) { rem -= 8 - ti; ++ti; }
  int tj = ti + rem;
  int m0 = ti * 64, n0 = tj * 64;
  __shared__ float As[32][64];
  __shared__ float Bs[32][64];
  int tid = threadIdx.x;
  int ty = tid >> 4, tx = tid & 15;
  float acc[4][4] = {};
  const float* Xb = X + (size_t)b * LL * MM;
  for (int l0 = z * 512; l0 < z * 512 + 512; l0 += 32) {
    int rr = tid >> 3, cc = (tid & 7) * 8;
    const float* p = Xb + (size_t)(l0 + rr) * MM + m0 + cc;
    const float* q = Xb + (size_t)(l0 + rr) * MM + n0 + cc;
    float4 a0 = *(const float4*)p;
    float4 a1 = *(const float4*)(p + 4);
    float4 c0 = *(const float4*)q;
    float4 c1 = *(const float4*)(q + 4);
    *(float4*)&As[rr][cc]     = a0;
    *(float4*)&As[rr][cc + 4] = a1;
    *(float4*)&Bs[rr][cc]     = c0;
    *(float4*)&Bs[rr][cc + 4] = c1;
    __syncthreads();
    #pragma unroll
    for (int kk = 0; kk < 32; ++kk) {
      float4 a4 = *(const float4*)&As[kk][ty * 4];
      float4 b4 = *(const float4*)&Bs[kk][tx * 4];
      acc[0][0] += a4.x * b4.x; acc[0][1] += a4.x * b4.y; acc[0][2] += a4.x * b4.z; acc[0][3] += a4.x * b4.w;
      acc[1][0] += a4.y * b4.x; acc[1][1] += a4.y * b4.y; acc[1][2] += a4.y * b4.z; acc[1][3] += a4.y * b4.w;
      acc[2][0] += a4.z * b4.x; acc[2][1] += a4.z * b4.y; acc[2][2] += a4.z * b4.z; acc[2][3] += a4.z * b4.w;
      acc[3][0] += a4.w * b4.x; acc[3][1] += a4.w * b4.y; acc[3][2] += a4.w * b4.z; acc[3][3] += a4.w * b4.w;
    }
    __syncthreads();
  }
  float* Gb = G + (size_t)b * MM * MM;
  #pragma unroll
  for (int i = 0; i < 4; ++i) {
    #pragma unroll
    for (int j = 0; j < 4; ++j) {
      int r = m0 + ty * 4 + i, c = n0 + tx * 4 + j;
      Gb[(size_t)r * MM + c] = acc[i][j];
      if (ti != tj) Gb[(size_t)c * MM + r] = acc[i][j];
    }
  }
}

// ---------------- rstd[b,m] = 1/std (std==0 -> 1) ----------------
__global__ void rstd_kernel(const float* __restrict__ G0, const float* __restrict__ G1,
                            const float* __restrict__ mu, float* __restrict__ rstd) {
  int bm = blockIdx.x * 256 + threadIdx.x;
  int b = bm >> 9, m = bm & (MM - 1);
  size_t di = (size_t)b * MM * MM + (size_t)m * MM + m;
  float g = G0[di] + G1[di];
  float mm = mu[bm];
  float cov = (g - 1024.f * mm * mm) * (1.f / 1023.f);
  float sd = sqrtf(fmaxf(cov, 0.f));
  rstd[bm] = (sd == 0.f) ? 1.f : (1.f / sd);
}

// ---------------- neighbors: ascending stable argsort positions 1..16 ----------------
__global__ void select_kernel(const float* __restrict__ G0, const float* __restrict__ G1,
                              const float* __restrict__ mu,
                              const float* __restrict__ rstd, int* __restrict__ nb) {
  int w = threadIdx.x >> 6, lane = threadIdx.x & 63;
  int bm = blockIdx.x * 4 + w;
  int b = bm >> 9, m = bm & (MM - 1);
  size_t rowoff = (size_t)b * MM * MM + (size_t)m * MM;
  const float* Gr0 = G0 + rowoff;
  const float* Gr1 = G1 + rowoff;
  const float* mub = mu + b * MM;
  const float* rsb = rstd + b * MM;
  float mm = mub[m], rm = rsb[m];
  float vals[8];
  int excl = 0;
  #pragma unroll
  for (int j = 0; j < 8; ++j) {
    int n = lane + j * 64;
    float cov = ((Gr0[n] + Gr1[n]) - 1024.f * mm * mub[n]) * (1.f / 1023.f);
    vals[j] = cov * rm * rsb[n];
  }
  int* out = nb + (size_t)bm * KK;
  for (int it = 0; it < KK + 1; ++it) {
    float bv = 1e30f; int bi = 1 << 30;
    #pragma unroll
    for (int j = 0; j < 8; ++j) {
      if (!((excl >> j) & 1)) {
        int n = lane + j * 64;
        if (vals[j] < bv) { bv = vals[j]; bi = n; }   // strict < keeps smaller n on ties
      }
    }
    for (int off = 32; off; off >>= 1) {
      float v2 = __shfl_down(bv, off);
      int   i2 = __shfl_down(bi, off);
      if (v2 < bv || (v2 == bv && i2 < bi)) { bv = v2; bi = i2; }
    }
    bi = __shfl(bi, 0);
    if ((bi & 63) == lane) excl |= 1 << (bi >> 6);
    if (it > 0 && lane == 0) out[it - 1] = bi;
  }
}

// ---------------- degree counts (without self-loop) ----------------
__global__ void count_kernel(const int* __restrict__ nb, int* __restrict__ cnt) {
  int e = blockIdx.x * 256 + threadIdx.x;           // < NEDGE
  int b = e >> 13, i = e & 8191;
  int dst = b * MM + nb[(size_t)b * 8192 + i];
  atomicAdd(&cnt[dst], 1);
}

// ---------------- exclusive scan + cursor + dinv (single block) ----------------
__global__ void scan_kernel(const int* __restrict__ cnt, int* __restrict__ offs,
                            int* __restrict__ curs, float* __restrict__ dinv) {
  __shared__ int part[256];
  int tid = threadIdx.x;
  int base = tid * 32;
  int local[32];
  int s = 0;
  #pragma unroll
  for (int i = 0; i < 32; ++i) { local[i] = cnt[base + i]; s += local[i]; }
  part[tid] = s;
  __syncthreads();
  for (int off = 1; off < 256; off <<= 1) {
    int v = (tid >= off) ? part[tid - off] : 0;
    __syncthreads();
    part[tid] += v;
    __syncthreads();
  }
  int run = part[tid] - s;
  #pragma unroll
  for (int i = 0; i < 32; ++i) {
    int n = base + i;
    offs[n] = run; curs[n] = run;
    run += local[i];
    dinv[n] = rsqrtf((float)(local[i] + 1));
  }
  if (tid == 255) offs[NNODE] = run;
}

// ---------------- scatter reverse edge lists ----------------
__global__ void scatter_kernel(const int* __restrict__ nb, int* __restrict__ curs,
                               int* __restrict__ lists) {
  int e = blockIdx.x * 256 + threadIdx.x;
  int b = e >> 13, i = e & 8191;
  int dst = b * MM + nb[(size_t)b * 8192 + i];
  int src = b * MM + (i & (MM - 1));
  int pos = atomicAdd(&curs[dst], 1);
  lists[pos] = src;
}

// ---------------- GCN aggregation ----------------
__global__ void agg_kernel(const float* __restrict__ xw, const float* __restrict__ dinv,
                           const int* __restrict__ offs, const int* __restrict__ lists,
                           const float* __restrict__ bias, float* __restrict__ out) {
  int n = blockIdx.x * 2 + (threadIdx.x >> 7);
  int c = threadIdx.x & 127;
  float dn = dinv[n];
  float s = dn * xw[(size_t)n * DD + c];
  int e0 = offs[n], e1 = offs[n + 1];
  for (int e = e0; e < e1; ++e) {
    int src = lists[e];
    s += dinv[src] * xw[(size_t)src * DD + c];
  }
  float v = dn * s + bias[c];
  out[(size_t)n * DD + c] = fmaxf(v, 0.f);
}

// ---------------- generic fp32 GEMM 64x64 tile ----------------
__global__ __launch_bounds__(256) void gemm_kernel(
    const float* __restrict__ A, const float* __restrict__ Bm, float* __restrict__ C,
    int N, int Kd, const float* __restrict__ bias,
    const float* __restrict__ resid, int relu) {
  __shared__ float As[64][36];
  __shared__ float Bs[32][64];
  int tid = threadIdx.x;
  int m0 = blockIdx.y * 64, n0 = blockIdx.x * 64;
  int ty = tid >> 4, tx = tid & 15;
  float acc[4][4] = {};
  for (int k0 = 0; k0 < Kd; k0 += 32) {
    {
      int row = tid >> 2, kc = (tid & 3) * 8;
      const float* ap = A + (size_t)(m0 + row) * Kd + k0 + kc;
      float4 v0 = *(const float4*)ap;
      float4 v1 = *(const float4*)(ap + 4);
      *(float4*)&As[row][kc]     = v0;
      *(float4*)&As[row][kc + 4] = v1;
      int brow = tid >> 3, nc = (tid & 7) * 8;
      const float* bp = Bm + (size_t)(k0 + brow) * N + n0 + nc;
      float4 w0 = *(const float4*)bp;
      float4 w1 = *(const float4*)(bp + 4);
      *(float4*)&Bs[brow][nc]     = w0;
      *(float4*)&Bs[brow][nc + 4] = w1;
    }
    __syncthreads();
    #pragma unroll
    for (int kk = 0; kk < 32; ++kk) {
      float a0 = As[ty * 4 + 0][kk];
      float a1 = As[ty * 4 + 1][kk];
      float a2 = As[ty * 4 + 2][kk];
      float a3 = As[ty * 4 + 3][kk];
      float4 b4 = *(const float4*)&Bs[kk][tx * 4];
      acc[0][0] += a0 * b4.x; acc[0][1] += a0 * b4.y; acc[0][2] += a0 * b4.z; acc[0][3] += a0 * b4.w;
      acc[1][0] += a1 * b4.x; acc[1][1] += a1 * b4.y; acc[1][2] += a1 * b4.z; acc[1][3] += a1 * b4.w;
      acc[2][0] += a2 * b4.x; acc[2][1] += a2 * b4.y; acc[2][2] += a2 * b4.z; acc[2][3] += a2 * b4.w;
      acc[3][0] += a3 * b4.x; acc[3][1] += a3 * b4.y; acc[3][2] += a3 * b4.z; acc[3][3] += a3 * b4.w;
    }
    __syncthreads();
  }
  #pragma unroll
  for (int i = 0; i < 4; ++i) {
    int r = m0 + ty * 4 + i;
    int cpos = n0 + tx * 4;
    float4 v = make_float4(acc[i][0], acc[i][1], acc[i][2], acc[i][3]);
    if (bias) {
      float4 bv = *(const float4*)&bias[cpos];
      v.x += bv.x; v.y += bv.y; v.z += bv.z; v.w += bv.w;
    }
    if (resid) {
      float4 rv = *(const float4*)&resid[(size_t)r * N + cpos];
      v.x += rv.x; v.y += rv.y; v.z += rv.z; v.w += rv.w;
    }
    if (relu) {
      v.x = fmaxf(v.x, 0.f); v.y = fmaxf(v.y, 0.f);
      v.z = fmaxf(v.z, 0.f); v.w = fmaxf(v.w, 0.f);
    }
    *(float4*)&C[(size_t)r * N + cpos] = v;
  }
}

// ---------------- fp32 GEMM 32x64 tile (2x blocks for narrow-N dispatches) ----------------
__global__ __launch_bounds__(256) void gemm32_kernel(
    const float* __restrict__ A, const float* __restrict__ Bm, float* __restrict__ C,
    int N, int Kd, const float* __restrict__ bias,
    const float* __restrict__ resid, int relu) {
  __shared__ float As[32][36];
  __shared__ float Bs[32][64];
  int tid = threadIdx.x;
  int m0 = blockIdx.y * 32, n0 = blockIdx.x * 64;
  int ty = tid >> 4, tx = tid & 15;          // ty: 0..15 -> rows ty*2, ty*2+1
  float acc[2][4] = {};
  for (int k0 = 0; k0 < Kd; k0 += 32) {
    {
      int row = tid >> 3, kc = (tid & 7) * 4;     // 32 rows x 32 k, float4 each
      const float* ap = A + (size_t)(m0 + row) * Kd + k0 + kc;
      *(float4*)&As[row][kc] = *(const float4*)ap;
      int brow = tid >> 3, nc = (tid & 7) * 8;
      const float* bp = Bm + (size_t)(k0 + brow) * N + n0 + nc;
      float4 w0 = *(const float4*)bp;
      float4 w1 = *(const float4*)(bp + 4);
      *(float4*)&Bs[brow][nc]     = w0;
      *(float4*)&Bs[brow][nc + 4] = w1;
    }
    __syncthreads();
    #pragma unroll
    for (int kk = 0; kk < 32; ++kk) {
      float a0 = As[ty * 2 + 0][kk];
      float a1 = As[ty * 2 + 1][kk];
      float4 b4 = *(const float4*)&Bs[kk][tx * 4];
      acc[0][0] += a0 * b4.x; acc[0][1] += a0 * b4.y; acc[0][2] += a0 * b4.z; acc[0][3] += a0 * b4.w;
      acc[1][0] += a1 * b4.x; acc[1][1] += a1 * b4.y; acc[1][2] += a1 * b4.z; acc[1][3] += a1 * b4.w;
    }
    __syncthreads();
  }
  #pragma unroll
  for (int i = 0; i < 2; ++i) {
    int r = m0 + ty * 2 + i;
    int cpos = n0 + tx * 4;
    float4 v = make_float4(acc[i][0], acc[i][1], acc[i][2], acc[i][3]);
    if (bias) {
      float4 bv = *(const float4*)&bias[cpos];
      v.x += bv.x; v.y += bv.y; v.z += bv.z; v.w += bv.w;
    }
    if (resid) {
      float4 rv = *(const float4*)&resid[(size_t)r * N + cpos];
      v.x += rv.x; v.y += rv.y; v.z += rv.z; v.w += rv.w;
    }
    if (relu) {
      v.x = fmaxf(v.x, 0.f); v.y = fmaxf(v.y, 0.f);
      v.z = fmaxf(v.z, 0.f); v.w = fmaxf(v.w, 0.f);
    }
    *(float4*)&C[(size_t)r * N + cpos] = v;
  }
}

// ---------------- fused attention (online softmax), dh=16, full 512 keys ----------------
#define KS(arr, r, j) arr[((r) << 4) + (((r) >> 6) << 3) + (j)]
__global__ __launch_bounds__(256) void attn_kernel(
    const float* __restrict__ qh, const float* __restrict__ kh,
    const float* __restrict__ vh, float* __restrict__ out) {
  __shared__ float ks[256 * 16 + 24];
  __shared__ float vs[256 * 16 + 24];
  int bx = blockIdx.x;
  int qc = bx & 7;
  int h  = (bx >> 3) & 7;
  int b  = bx >> 6;
  int tid = threadIdx.x;
  int r = tid >> 2;
  int p = tid & 3;
  int qrow = b * MM + qc * 64 + r;
  float qv[16];
  const float* qp = qh + (size_t)qrow * DD + h * DHH;
  #pragma unroll
  for (int j = 0; j < 16; ++j) qv[j] = qp[j];
  float mval = -1e30f, l = 0.f;
  float o[16];
  #pragma unroll
  for (int j = 0; j < 16; ++j) o[j] = 0.f;
  for (int ch = 0; ch < 2; ++ch) {
    __syncthreads();
    for (int idx = tid; idx < 256 * 4; idx += 256) {
      int row = idx >> 2, seg = idx & 3;
      int krow = b * MM + ch * 256 + row;
      *(float4*)&KS(ks, row, seg * 4) = *(const float4*)&kh[(size_t)krow * DD + h * DHH + seg * 4];
      *(float4*)&KS(vs, row, seg * 4) = *(const float4*)&vh[(size_t)krow * DD + h * DHH + seg * 4];
    }
    __syncthreads();
    for (int kk = p * 64; kk < p * 64 + 64; ++kk) {
      float s = 0.f;
      #pragma unroll
      for (int j = 0; j < 16; ++j) s += qv[j] * KS(ks, kk, j);
      s *= 0.25f;
      float nm = fmaxf(mval, s);
      float scale = __expf(mval - nm);
      float pw = __expf(s - nm);
      l = l * scale + pw;
      #pragma unroll
      for (int j = 0; j < 16; ++j) o[j] = o[j] * scale + pw * KS(vs, kk, j);
      mval = nm;
    }
  }
  #pragma unroll
  for (int off = 1; off <= 2; off <<= 1) {
    float m2 = __shfl_xor(mval, off);
    float l2 = __shfl_xor(l, off);
    float nm = fmaxf(mval, m2);
    float s1 = __expf(mval - nm), s2 = __expf(m2 - nm);
    l = l * s1 + l2 * s2;
    #pragma unroll
    for (int j = 0; j < 16; ++j) {
      float o2 = __shfl_xor(o[j], off);
      o[j] = o[j] * s1 + o2 * s2;
    }
    mval = nm;
  }
  if (p == 0) {
    float invl = 1.f / l;
    float* op = out + (size_t)qrow * DD + h * DHH;
    #pragma unroll
    for (int j = 0; j < 16; ++j) op[j] = o[j] * invl;
  }
}

// ---------------- layernorm over D=128 ----------------
__global__ void ln_kernel(const float* __restrict__ x, const float* __restrict__ g,
                          const float* __restrict__ bb, float* __restrict__ out) {
  int row = blockIdx.x * 4 + (threadIdx.x >> 6);
  int lane = threadIdx.x & 63;
  float2 xv = *(const float2*)&x[(size_t)row * DD + lane * 2];
  float s = xv.x + xv.y;
  #pragma unroll
  for (int off = 1; off < 64; off <<= 1) s += __shfl_xor(s, off);
  float mu = s * (1.f / 128.f);
  float d0 = xv.x - mu, d1 = xv.y - mu;
  float sq = d0 * d0 + d1 * d1;
  #pragma unroll
  for (int off = 1; off < 64; off <<= 1) sq += __shfl_xor(sq, off);
  float rs = rsqrtf(sq * (1.f / 128.f) + 1e-5f);
  float2 gg = *(const float2*)&g[lane * 2];
  float2 bv = *(const float2*)&bb[lane * 2];
  float2 y;
  y.x = d0 * rs * gg.x + bv.x;
  y.y = d1 * rs * gg.y + bv.y;
  *(float2*)&out[(size_t)row * DD + lane * 2] = y;
}

extern "C" void kernel_launch(void* const* d_in, const int* in_sizes, int n_in,
                              void* d_out, int out_size, void* d_ws, size_t ws_size,
                              hipStream_t stream) {
  (void)in_sizes; (void)n_in; (void)out_size; (void)ws_size;
  const float* enc  = (const float*)d_in[0];
  const float* xenc = (const float*)d_in[1];
  const float* gw1  = (const float*)d_in[2];
  const float* gb1  = (const float*)d_in[3];
  const float* gw2  = (const float*)d_in[4];
  const float* gb2  = (const float*)d_in[5];
  const float* Wq   = (const float*)d_in[6];
  const float* Wk   = (const float*)d_in[7];
  const float* Wv   = (const float*)d_in[8];
  const float* Wo   = (const float*)d_in[9];
  const float* ln1g = (const float*)d_in[10];
  const float* ln1b = (const float*)d_in[11];
  const float* W1   = (const float*)d_in[12];
  const float* b1   = (const float*)d_in[13];
  const float* W2   = (const float*)d_in[14];
  const float* b2   = (const float*)d_in[15];
  const float* ln2g = (const float*)d_in[16];
  const float* ln2b = (const float*)d_in[17];
  float* outp = (float*)d_out;

  char* w = (char*)d_ws;
  auto alloc = [&](size_t bytes) -> char* {
    char* p = w;
    w += (bytes + 255) & ~(size_t)255;
    return p;
  };
  float* mu    = (float*)alloc((size_t)NNODE * 4);
  float* rstd  = (float*)alloc((size_t)NNODE * 4);
  float* dinv  = (float*)alloc((size_t)NNODE * 4);
  float* mpart = (float*)alloc((size_t)8 * NNODE * 4);
  int*   nb    = (int*)  alloc((size_t)NEDGE * 4);
  int*   cnt   = (int*)  alloc((size_t)NNODE * 4);
  int*   offs  = (int*)  alloc((size_t)(NNODE + 1) * 4);
  int*   curs  = (int*)  alloc((size_t)NNODE * 4);
  int*   lists = (int*)  alloc((size_t)NEDGE * 4);
  float* gram  = (float*)alloc((size_t)BB * MM * MM * 4);        // 16 MB, reused
  float* kvb   = (float*)alloc((size_t)NNODE * DD * 4);
  float* bufx  = (float*)alloc((size_t)NNODE * DD * 4);
  float* bufxl = (float*)alloc((size_t)NNODE * DD * 4);
  float* bufh  = (float*)alloc((size_t)NNODE * DD * 4);
  float* bufh1 = (float*)alloc((size_t)NNODE * DD * 4);
  float* SA = gram;
  float* SB = gram + (size_t)1048576;
  float* SC = gram + (size_t)2097152;
  float* SD = gram + (size_t)3145728;
  // Second gram partial aliases kvb..bufh (16 MB) — dead until after select_kernel.
  float* gram2 = kvb;

  auto gemm = [&](const float* A, const float* Bm, float* C, int Mr, int N, int Kd,
                  const float* bias, const float* resid, int relu) {
    if (N == 128) {
      dim3 g(N / 64, Mr / 32);
      gemm32_kernel<<<g, 256, 0, stream>>>(A, Bm, C, N, Kd, bias, resid, relu);
    } else {
      dim3 g(N / 64, Mr / 64);
      gemm_kernel<<<g, 256, 0, stream>>>(A, Bm, C, N, Kd, bias, resid, relu);
    }
  };

  // ---- graph build ----
  colmean_part_kernel<<<dim3(32, 8), 256, 0, stream>>>(xenc, mpart);
  colmean_finish_kernel<<<NNODE / 256, 256, 0, stream>>>(mpart, mu);
  gram_kernel<<<dim3(36, BB, 2), 256, 0, stream>>>(xenc, gram, gram2);
  rstd_kernel<<<NNODE / 256, 256, 0, stream>>>(gram, gram2, mu, rstd);
  select_kernel<<<NNODE / 4, 256, 0, stream>>>(gram, gram2, mu, rstd, nb);
  hipMemsetAsync(cnt, 0, (size_t)NNODE * 4, stream);
  count_kernel<<<NEDGE / 256, 256, 0, stream>>>(nb, cnt);
  scan_kernel<<<1, 256, 0, stream>>>(cnt, offs, curs, dinv);
  scatter_kernel<<<NEDGE / 256, 256, 0, stream>>>(nb, curs, lists);

  // ---- 2-layer GCN ----
  gemm(enc, gw1, SA, NNODE, DD, DD, nullptr, nullptr, 0);
  agg_kernel<<<NNODE / 2, 256, 0, stream>>>(SA, dinv, offs, lists, gb1, SB);
  gemm(SB, gw2, SC, NNODE, DD, DD, nullptr, nullptr, 0);
  agg_kernel<<<NNODE / 2, 256, 0, stream>>>(SC, dinv, offs, lists, gb2, kvb);

  // ---- transformer encoder layers ----
  for (int l = 0; l < 2; ++l) {
    const float* hq = (l == 0) ? enc : bufh1;
    const float* Wql = Wq + (size_t)l * DD * DD;
    const float* Wkl = Wk + (size_t)l * DD * DD;
    const float* Wvl = Wv + (size_t)l * DD * DD;
    const float* Wol = Wo + (size_t)l * DD * DD;
    gemm(hq,  Wql, SA, NNODE, DD, DD, nullptr, nullptr, 0);
    gemm(kvb, Wkl, SB, NNODE, DD, DD, nullptr, nullptr, 0);
    gemm(kvb, Wvl, SC, NNODE, DD, DD, nullptr, nullptr, 0);
    attn_kernel<<<BB * HH * 8, 256, 0, stream>>>(SA, SB, SC, SD);
    gemm(SD, Wol, bufx, NNODE, DD, DD, nullptr, hq, 0);
    ln_kernel<<<NNODE / 4, 256, 0, stream>>>(bufx, ln1g + l * DD, ln1b + l * DD, bufxl);
    gemm(bufxl, W1 + (size_t)l * DD * NDFF, gram, NNODE, NDFF, DD,
         b1 + l * NDFF, nullptr, 1);
    gemm(gram, W2 + (size_t)l * NDFF * DD, bufh, NNODE, DD, NDFF,
         b2 + l * DD, bufxl, 0);
    ln_kernel<<<NNODE / 4, 256, 0, stream>>>(bufh, ln2g + l * DD, ln2b + l * DD,
                                             (l == 1) ? outp : bufh1);
  }
}